// Round 8
// baseline (294.548 us; speedup 1.0000x reference)
//
#include <hip/hip_runtime.h>
#include <hip/hip_bf16.h>
#include <math.h>

typedef __attribute__((ext_vector_type(8))) short short8;
typedef __attribute__((ext_vector_type(4))) float floatx4;
typedef unsigned short u16;
typedef unsigned int u32;

__device__ __forceinline__ float b2f(u16 v) {
    union { u32 i; float f; } x; x.i = ((u32)v) << 16; return x.f;
}
__device__ __forceinline__ u16 f2b(float f) {
    union { u32 i; float f; } x; x.f = f;
    u32 r = x.i + 0x7FFFu + ((x.i >> 16) & 1u);
    return (u16)(r >> 16);
}

// async global->LDS, 16B per lane (wave-uniform base + lane*16 layout)
__device__ __forceinline__ void gload_lds16(const u16* g, short* l) {
    __builtin_amdgcn_global_load_lds((const __attribute__((address_space(1))) void*)g,
                                     (__attribute__((address_space(3))) void*)l, 16, 0, 0);
}

#define BM 128
#define BN 128
#define BKg 64
#define NCHUNK 16
#define CT 64   // timesteps per chunk

// one-shot convert of all 5 f32 operand arrays to bf16 (float4 granularity)
__global__ void convert_all(const float* __restrict__ s0, u16* __restrict__ d0,
                            const float* __restrict__ s1, u16* __restrict__ d1,
                            const float* __restrict__ s2, u16* __restrict__ d2,
                            const float* __restrict__ s3, u16* __restrict__ d3,
                            const float* __restrict__ s4, u16* __restrict__ d4)
{
    int i = blockIdx.x * 256 + threadIdx.x;
    const float* src; u16* dst;
    if (i < 524288)            { src = s0; dst = d0; }
    else if (i < 1572864)      { src = s1; dst = d1; i -= 524288; }
    else if (i < 1622016)      { src = s2; dst = d2; i -= 1572864; }
    else if (i < 1654784)      { src = s3; dst = d3; i -= 1622016; }
    else if (i < 2179072)      { src = s4; dst = d4; i -= 1654784; }
    else return;
    float4 v = ((const float4*)src)[i];
    ushort4 o;
    o.x = f2b(v.x); o.y = f2b(v.y); o.z = f2b(v.z); o.w = f2b(v.w);
    ((ushort4*)dst)[i] = o;
}

// NT GEMM: C[m,n] = sum_k A[m,k]*B[n,k]; A:[M,lda] bf16, B:[N,ldb] bf16.
// global_load_lds (16B) staging, unpadded LDS (m97 structure).
// EPI: 1 = bf16 store, 5 = f32 partial store at Cout + z*M*ldc (split-K),
//      6 = +bias[n] (f32), softplus, bf16 store
template<int EPI>
__global__ __launch_bounds__(256, 4)
void gemm_nt(const u16* __restrict__ A, const u16* __restrict__ B,
             void* __restrict__ Cout, const float* __restrict__ bias,
             int M, int N, int K_per_split, int lda, int ldb, int ldc)
{
    __shared__ __align__(16) short As[BM][BKg];   // 16 KB, unpadded (lds-dma layout)
    __shared__ __align__(16) short Bs[BN][BKg];   // 16 KB

    const int tid  = threadIdx.x;
    const int wave = tid >> 6;
    const int lane = tid & 63;
    const int m0 = blockIdx.x * BM;
    const int n0 = blockIdx.y * BN;
    const int k_begin = blockIdx.z * K_per_split;

    const int wm = (wave & 1) * 64;
    const int wn = (wave >> 1) * 64;

    floatx4 acc[4][4];
#pragma unroll
    for (int i = 0; i < 4; i++)
#pragma unroll
        for (int j = 0; j < 4; j++) acc[i][j] = (floatx4)(0.f);

    // staging map: call j covers tile row r = wave*32 + j*8 + (lane>>3),
    // cols [(lane&7)*8, +8). LDS byte addr == waveBase + lane*16 (contiguous).
    const int srow = wave * 32 + (lane >> 3);
    const int scol = (lane & 7) * 8;

    for (int k0 = 0; k0 < K_per_split; k0 += BKg) {
        const int kg = k_begin + k0;
        __syncthreads();   // protect LDS from overwrite while prior iter still reading
#pragma unroll
        for (int j = 0; j < 4; j++) {
            const int r = srow + j * 8;
            gload_lds16(A + (size_t)(m0 + r) * lda + kg + scol, &As[r][scol]);
        }
#pragma unroll
        for (int j = 0; j < 4; j++) {
            const int r = srow + j * 8;
            if (n0 + r < N)   // masked lanes leave stale LDS -> only affects discarded cols
                gload_lds16(B + (size_t)(n0 + r) * ldb + kg + scol, &Bs[r][scol]);
        }
        __syncthreads();   // drains vmcnt (lds-dma complete)
#pragma unroll
        for (int kk = 0; kk < 2; kk++) {
            const int ko = kk * 32 + (lane >> 4) * 8;
            short8 af[4], bfr[4];
#pragma unroll
            for (int i = 0; i < 4; i++)
                af[i] = *(const short8*)&As[wm + i * 16 + (lane & 15)][ko];
#pragma unroll
            for (int j = 0; j < 4; j++)
                bfr[j] = *(const short8*)&Bs[wn + j * 16 + (lane & 15)][ko];
#pragma unroll
            for (int i = 0; i < 4; i++)
#pragma unroll
                for (int j = 0; j < 4; j++)
                    acc[i][j] = __builtin_amdgcn_mfma_f32_16x16x32_bf16(
                        af[i], bfr[j], acc[i][j], 0, 0, 0);
        }
    }

    // Epilogue. C/D layout: col(n)=lane&15, row(m)=(lane>>4)*4+reg  [m89-verified]
    const int cn0 = n0 + wn + (lane & 15);
    const int cm0 = m0 + wm + ((lane >> 4) << 2);
    const size_t zoff = (size_t)blockIdx.z * M * ldc;
#pragma unroll
    for (int i = 0; i < 4; i++) {
#pragma unroll
        for (int j = 0; j < 4; j++) {
            const int n = cn0 + j * 16;
            if (n < N) {
#pragma unroll
                for (int r = 0; r < 4; r++) {
                    const int m = cm0 + i * 16 + r;
                    float v = acc[i][j][r];
                    const size_t off = (size_t)m * ldc + n;
                    if constexpr (EPI == 1) {
                        ((u16*)Cout)[off] = f2b(v);
                    } else if constexpr (EPI == 6) { // bias + softplus -> bf16
                        v += bias[n];
                        float sp = (v > 15.f) ? v : log1pf(__expf(v));
                        ((u16*)Cout)[off] = f2b(sp);
                    } else { // 5: f32 partial store (split-K)
                        ((float*)Cout)[zoff + off] = v;
                    }
                }
            }
        }
    }
}

// reduce 16 split-K partials of x_dbl -> xdblf (f32) + xdblb (bf16)
__global__ void reduce_xdbl(const float* __restrict__ part, float* __restrict__ of,
                            u16* __restrict__ ob)
{
    const int i = blockIdx.x * 256 + threadIdx.x;   // float4 index, [0, 49152)
    if (i >= 49152) return;
    const size_t MN4 = 49152;
    float4 s = ((const float4*)part)[i];
#pragma unroll
    for (int z = 1; z < 16; z++) {
        const float4 p = ((const float4*)part)[z * MN4 + i];
        s.x += p.x; s.y += p.y; s.z += p.z; s.w += p.w;
    }
    ((float4*)of)[i] = s;
    ushort4 o;
    o.x = f2b(s.x); o.y = f2b(s.y); o.z = f2b(s.z); o.w = f2b(s.w);
    ((ushort4*)ob)[i] = o;
}

// reduce 4 split-K partials of out -> f32 out
__global__ void reduce_out(const float* __restrict__ part, float* __restrict__ out)
{
    const int i = blockIdx.x * 256 + threadIdx.x;   // float4 index, [0, 524288)
    const size_t MN4 = 524288;
    float4 s = ((const float4*)part)[i];
#pragma unroll
    for (int z = 1; z < 4; z++) {
        const float4 p = ((const float4*)part)[z * MN4 + i];
        s.x += p.x; s.y += p.y; s.z += p.z; s.w += p.w;
    }
    ((float4*)out)[i] = s;
}

// causal depthwise conv (width 4) + SiLU
__global__ void conv_silu_kernel(const u16* __restrict__ xz, const float* __restrict__ cw,
                                 const float* __restrict__ cb, u16* __restrict__ u)
{
    const int idx = blockIdx.x * 256 + threadIdx.x;   // [0, 2*1024*2048)
    const int d = idx & 2047;
    const int row = idx >> 11;
    const int l = row & 1023;
    float acc = cb[d];
#pragma unroll
    for (int j = 0; j < 4; j++) {
        const int lj = l - 3 + j;
        if (lj >= 0)
            acc += cw[d * 4 + j] * b2f(xz[(size_t)(row - 3 + j) * 4096 + d]);
    }
    const float s = acc / (1.f + __expf(-acc));
    u[(size_t)row * 2048 + d] = f2b(s);
}

// ---- chunked selective scan, 8 states per thread, LDS-staged inputs ----
// delta is bf16 now.
__global__ __launch_bounds__(256)
void scan_pass1(const u16* __restrict__ delta, const u16* __restrict__ u,
                const float* __restrict__ xdbl, const float* __restrict__ A_log,
                float* __restrict__ aP, float* __restrict__ hpart)
{
    __shared__ u16   dS[CT * 128];   // 16 KB
    __shared__ u16   uS[CT * 128];   // 16 KB
    __shared__ float BS[CT * 16];    //  4 KB

    const int tid  = threadIdx.x;
    const int half = tid & 1;
    const int dloc = tid >> 1;
    const int d0 = blockIdx.x * 128;
    const int d = d0 + dloc;
    const int b = blockIdx.y >> 4;
    const int chunk = blockIdx.y & 15;
    const int bd = b * 2048 + d;
    const size_t row0 = (size_t)b * 1024 + chunk * CT;

    for (int i = tid; i < CT * 128 / 8; i += 256) {
        const int e = i * 8;
        const int t = e >> 7, c = e & 127;
        *(uint4*)&dS[e] = *(const uint4*)&delta[(row0 + t) * 2048 + d0 + c];
        *(uint4*)&uS[e] = *(const uint4*)&u[(row0 + t) * 2048 + d0 + c];
    }
    for (int i = tid; i < CT * 16; i += 256) {
        const int t = i >> 4, n = i & 15;
        BS[i] = xdbl[(row0 + t) * 96 + 64 + n];
    }

    float A_dn[8], h[8], ap[8];
#pragma unroll
    for (int j = 0; j < 8; j++) {
        A_dn[j] = -__expf(A_log[d * 16 + half * 8 + j]);
        h[j] = 0.f; ap[j] = 1.f;
    }
    __syncthreads();

#pragma unroll 4
    for (int t = 0; t < CT; t++) {
        const float dl = b2f(dS[t * 128 + dloc]);
        const float uu = b2f(uS[t * 128 + dloc]);
        const float dlu = dl * uu;
        const float4 B0 = *(const float4*)&BS[t * 16 + half * 8];
        const float4 B1 = *(const float4*)&BS[t * 16 + half * 8 + 4];
        const float Bv[8] = {B0.x, B0.y, B0.z, B0.w, B1.x, B1.y, B1.z, B1.w};
#pragma unroll
        for (int j = 0; j < 8; j++) {
            const float dA = __expf(dl * A_dn[j]);
            h[j] = dA * h[j] + dlu * Bv[j];
            ap[j] *= dA;
        }
    }

    const size_t o = ((size_t)(bd * 16 + chunk) * 16) + half * 8;
    *(float4*)&aP[o]     = make_float4(ap[0], ap[1], ap[2], ap[3]);
    *(float4*)&aP[o + 4] = make_float4(ap[4], ap[5], ap[6], ap[7]);
    *(float4*)&hpart[o]     = make_float4(h[0], h[1], h[2], h[3]);
    *(float4*)&hpart[o + 4] = make_float4(h[4], h[5], h[6], h[7]);
}

__global__ void scan_combine(const float* __restrict__ aP, float* __restrict__ hp)
{
    const int idx = blockIdx.x * 256 + threadIdx.x;  // [0, 65536) = bd*16 + n
    const int n = idx & 15;
    const int bd = idx >> 4;
    float h = 0.f;
    for (int c = 0; c < NCHUNK; c++) {
        const size_t o = ((size_t)(bd * 16 + c) * 16) + n;
        const float a = aP[o];
        const float p = hp[o];
        hp[o] = h;          // exclusive prefix = h_init for chunk c
        h = a * h + p;
    }
}

__global__ __launch_bounds__(256)
void scan_pass2(const u16* __restrict__ delta, const u16* __restrict__ u,
                const float* __restrict__ xdbl, const u16* __restrict__ xz,
                const float* __restrict__ A_log, const float* __restrict__ Dv,
                const float* __restrict__ hinit, u16* __restrict__ ybuf)
{
    __shared__ u16   dS[CT * 128];   // 16 KB
    __shared__ u16   uS[CT * 128];   // 16 KB
    __shared__ u16   zS[CT * 128];   // 16 KB
    __shared__ float BS[CT * 16];    //  4 KB
    __shared__ float CS[CT * 16];    //  4 KB

    const int tid  = threadIdx.x;
    const int half = tid & 1;
    const int dloc = tid >> 1;
    const int d0 = blockIdx.x * 128;
    const int d = d0 + dloc;
    const int b = blockIdx.y >> 4;
    const int chunk = blockIdx.y & 15;
    const int bd = b * 2048 + d;
    const size_t row0 = (size_t)b * 1024 + chunk * CT;

    for (int i = tid; i < CT * 128 / 8; i += 256) {
        const int e = i * 8;
        const int t = e >> 7, c = e & 127;
        *(uint4*)&dS[e] = *(const uint4*)&delta[(row0 + t) * 2048 + d0 + c];
        *(uint4*)&uS[e] = *(const uint4*)&u[(row0 + t) * 2048 + d0 + c];
        *(uint4*)&zS[e] = *(const uint4*)&xz[(row0 + t) * 4096 + 2048 + d0 + c];
    }
    for (int i = tid; i < CT * 16; i += 256) {
        const int t = i >> 4, n = i & 15;
        BS[i] = xdbl[(row0 + t) * 96 + 64 + n];
        CS[i] = xdbl[(row0 + t) * 96 + 80 + n];
    }

    const size_t o = ((size_t)(bd * 16 + chunk) * 16) + half * 8;
    const float4 h0 = *(const float4*)&hinit[o];
    const float4 h1 = *(const float4*)&hinit[o + 4];
    float h[8] = {h0.x, h0.y, h0.z, h0.w, h1.x, h1.y, h1.z, h1.w};
    float A_dn[8];
#pragma unroll
    for (int j = 0; j < 8; j++)
        A_dn[j] = -__expf(A_log[d * 16 + half * 8 + j]);
    const float Dd = Dv[d];
    __syncthreads();

#pragma unroll 4
    for (int t = 0; t < CT; t++) {
        const float dl = b2f(dS[t * 128 + dloc]);
        const float uu = b2f(uS[t * 128 + dloc]);
        const float dlu = dl * uu;
        const float4 B0 = *(const float4*)&BS[t * 16 + half * 8];
        const float4 B1 = *(const float4*)&BS[t * 16 + half * 8 + 4];
        const float4 C0 = *(const float4*)&CS[t * 16 + half * 8];
        const float4 C1 = *(const float4*)&CS[t * 16 + half * 8 + 4];
        const float Bv[8] = {B0.x, B0.y, B0.z, B0.w, B1.x, B1.y, B1.z, B1.w};
        const float Cv[8] = {C0.x, C0.y, C0.z, C0.w, C1.x, C1.y, C1.z, C1.w};
        float p = 0.f;
#pragma unroll
        for (int j = 0; j < 8; j++) {
            const float dA = __expf(dl * A_dn[j]);
            h[j] = dA * h[j] + dlu * Bv[j];
            p += h[j] * Cv[j];
        }
        p += __shfl_xor(p, 1);
        if (half == 0) {
            const float z = b2f(zS[t * 128 + dloc]);
            const float gt = z / (1.f + __expf(-z));
            ybuf[(row0 + t) * 2048 + d] = f2b((p + uu * Dd) * gt);
        }
    }
}

extern "C" void kernel_launch(void* const* d_in, const int* in_sizes, int n_in,
                              void* d_out, int out_size, void* d_ws, size_t ws_size,
                              hipStream_t stream)
{
    const float* hid    = (const float*)d_in[0];  // [2,1024,1024]
    const float* w_in   = (const float*)d_in[1];  // [4096,1024]
    const float* conv_w = (const float*)d_in[2];  // [2048,1,4]
    const float* conv_b = (const float*)d_in[3];  // [2048]
    const float* w_x    = (const float*)d_in[4];  // [96,2048]
    const float* w_dt   = (const float*)d_in[5];  // [2048,64]
    const float* b_dt   = (const float*)d_in[6];  // [2048]
    const float* A_log  = (const float*)d_in[7];  // [2048,16]
    const float* Dvec   = (const float*)d_in[8];  // [2048]
    const float* w_out  = (const float*)d_in[9];  // [1024,2048]
    float* out = (float*)d_out;                   // [2,1024,1024] f32

    const size_t MB = 1048576;
    char* ws = (char*)d_ws;
    // region 0-40 MB, time-multiplexed:
    //   phase A (GEMM1..pass2): xz 0-16, ubuf 16-24, [part3 24-37 then delta(bf16) 24-32]
    //   phase B (GEMM6+reduce): part6 0-32 (xz/ubuf/delta dead)
    u16*   xz     = (u16*)(ws + 0);                  // 16 MB  [2048,4096] bf16
    u16*   ubuf   = (u16*)(ws + 16 * MB);            //  8 MB  [2048,2048] bf16
    float* part3  = (float*)(ws + 24 * MB);          // 12.6 MB (16 × 2048×96 f32)
    u16*   delta  = (u16*)(ws + 24 * MB);            //  8 MB [2048,2048] bf16 (after part3 dead)
    float* part6  = (float*)(ws + 0);                // 32 MB (4 × 2048×1024 f32)
    float* xdblf  = (float*)(ws + 40 * MB);          // 768 KB [2048,96] f32
    u16*   xdblb  = (u16*)(ws + 40 * MB + 786432);   // 384 KB [2048,96] bf16
    u16*   w_x_b  = (u16*)(ws + 41 * MB + 131072);   // 384 KB
    u16*   w_dt_b = (u16*)(ws + 41 * MB + 524288);   // 256 KB
    u16*   hid_b  = (u16*)(ws + 42 * MB);            // 4 MB (GEMM1 only)
    float* hpart  = (float*)(ws + 42 * MB);          // 4 MB (65536*16 f32) — after hid_b dead
    u16*   w_in_b = (u16*)(ws + 46 * MB);            // 8 MB (GEMM1 only)
    float* aP     = (float*)(ws + 50 * MB);          // 4 MB — after w_in_b dead
    u16*   ybuf   = (u16*)(ws + 46 * MB);            // 8 MB — pass2 writes after aP dead
    u16*   w_out_b= (u16*)(ws + 54 * MB);            // 4 MB
    // total footprint: 58 MB

    // 0) convert all f32 operands to bf16 (single launch)
    convert_all<<<8512, 256, 0, stream>>>(hid, hid_b, w_in, w_in_b, w_x, w_x_b,
                                          w_dt, w_dt_b, w_out, w_out_b);

    // 1) xz = hidden @ in_proj_w.T   [2048,4096]
    gemm_nt<1><<<dim3(16, 32, 1), 256, 0, stream>>>(hid_b, w_in_b, xz, nullptr,
                                                    2048, 4096, 1024, 1024, 1024, 4096);
    // 2) u = silu(causal_conv(x))    [2048,2048]
    conv_silu_kernel<<<16384, 256, 0, stream>>>(xz, conv_w, conv_b, ubuf);
    // 3) x_dbl = u @ x_proj_w.T      [2048,96]  (split-K 16, partials + reduce)
    gemm_nt<5><<<dim3(16, 1, 16), 256, 0, stream>>>(ubuf, w_x_b, part3, nullptr,
                                                    2048, 96, 128, 2048, 2048, 96);
    reduce_xdbl<<<192, 256, 0, stream>>>(part3, xdblf, xdblb);
    // 4) delta = softplus(dt_low @ dt_proj_w.T + dt_proj_b)   [2048,2048] bf16
    gemm_nt<6><<<dim3(16, 16, 1), 256, 0, stream>>>(xdblb, w_dt_b, delta, b_dt,
                                                    2048, 2048, 64, 96, 64, 2048);
    // 5) chunked selective scan + skip + gate -> ybuf [2048,2048] bf16
    scan_pass1<<<dim3(16, 32), 256, 0, stream>>>(delta, ubuf, xdblf, A_log, aP, hpart);
    scan_combine<<<256, 256, 0, stream>>>(aP, hpart);
    scan_pass2<<<dim3(16, 32), 256, 0, stream>>>(delta, ubuf, xdblf, xz, A_log, Dvec,
                                                 hpart, ybuf);
    // 6) out = y @ out_proj_w.T      [2048,1024]  (split-K 4, partials + reduce)
    gemm_nt<5><<<dim3(16, 8, 4), 256, 0, stream>>>(ybuf, w_out_b, part6, nullptr,
                                                   2048, 1024, 512, 2048, 2048, 1024);
    reduce_out<<<2048, 256, 0, stream>>>(part6, out);
}

// Round 9
// 260.500 us; speedup vs baseline: 1.1307x; 1.1307x over previous
//
#include <hip/hip_runtime.h>
#include <hip/hip_bf16.h>
#include <math.h>

typedef __attribute__((ext_vector_type(8))) short short8;
typedef __attribute__((ext_vector_type(4))) float floatx4;
typedef unsigned short u16;
typedef unsigned int u32;

__device__ __forceinline__ float b2f(u16 v) {
    union { u32 i; float f; } x; x.i = ((u32)v) << 16; return x.f;
}
__device__ __forceinline__ u16 f2b(float f) {
    union { u32 i; float f; } x; x.f = f;
    u32 r = x.i + 0x7FFFu + ((x.i >> 16) & 1u);
    return (u16)(r >> 16);
}

// async global->LDS, 16B per lane (wave-uniform base + lane*16 layout)
__device__ __forceinline__ void gload_lds16(const u16* g, short* l) {
    __builtin_amdgcn_global_load_lds((const __attribute__((address_space(1))) void*)g,
                                     (__attribute__((address_space(3))) void*)l, 16, 0, 0);
}

#define BM 128
#define BN 128
#define BKg 64
#define NCHUNK 16
#define CT 64   // timesteps per chunk

// one-shot convert of all 5 f32 operand arrays to bf16 (float4 granularity)
__global__ void convert_all(const float* __restrict__ s0, u16* __restrict__ d0,
                            const float* __restrict__ s1, u16* __restrict__ d1,
                            const float* __restrict__ s2, u16* __restrict__ d2,
                            const float* __restrict__ s3, u16* __restrict__ d3,
                            const float* __restrict__ s4, u16* __restrict__ d4)
{
    int i = blockIdx.x * 256 + threadIdx.x;
    const float* src; u16* dst;
    if (i < 524288)            { src = s0; dst = d0; }
    else if (i < 1572864)      { src = s1; dst = d1; i -= 524288; }
    else if (i < 1622016)      { src = s2; dst = d2; i -= 1572864; }
    else if (i < 1654784)      { src = s3; dst = d3; i -= 1622016; }
    else if (i < 2179072)      { src = s4; dst = d4; i -= 1654784; }
    else return;
    float4 v = ((const float4*)src)[i];
    ushort4 o;
    o.x = f2b(v.x); o.y = f2b(v.y); o.z = f2b(v.z); o.w = f2b(v.w);
    ((ushort4*)dst)[i] = o;
}

// NT GEMM: C[m,n] = sum_k A[m,k]*B[n,k]; A:[M,lda] bf16, B:[N,ldb] bf16.
// DMA=true: global_load_lds staging (unpadded LDS) — use for many-K-iter, big-grid GEMMs.
// DMA=false: VGPR staging (padded LDS) — use for short-K / small-grid GEMMs where the
//            per-iteration vmcnt(0)+barrier drain of the DMA path is fully exposed
//            (measured: GEMM4 K=64, 256 blocks went 110 us with DMA vs ~15 us without).
// EPI: 1 = bf16 store, 5 = f32 partial store at Cout + z*M*ldc (split-K),
//      6 = +bias[n] (f32), softplus, bf16 store
template<int EPI, bool DMA>
__global__ __launch_bounds__(256, DMA ? 4 : 2)
void gemm_nt(const u16* __restrict__ A, const u16* __restrict__ B,
             void* __restrict__ Cout, const float* __restrict__ bias,
             int M, int N, int K_per_split, int lda, int ldb, int ldc)
{
    constexpr int LDW = BKg + (DMA ? 0 : 8);   // row stride in shorts
    __shared__ __align__(16) short As[BM * LDW];
    __shared__ __align__(16) short Bs[BN * LDW];

    const int tid  = threadIdx.x;
    const int wave = tid >> 6;
    const int lane = tid & 63;
    const int m0 = blockIdx.x * BM;
    const int n0 = blockIdx.y * BN;
    const int k_begin = blockIdx.z * K_per_split;

    const int wm = (wave & 1) * 64;
    const int wn = (wave >> 1) * 64;

    floatx4 acc[4][4];
#pragma unroll
    for (int i = 0; i < 4; i++)
#pragma unroll
        for (int j = 0; j < 4; j++) acc[i][j] = (floatx4)(0.f);

    // DMA staging map: call j covers row r = wave*32 + j*8 + (lane>>3),
    // cols [(lane&7)*8, +8); LDS byte addr == waveBase + lane*16.
    const int srow = wave * 32 + (lane >> 3);
    const int scol = (lane & 7) * 8;
    // VGPR staging map: row tid>>1, col halves of 32
    const int vrow = tid >> 1;
    const int vcol = (tid & 1) * 32;

    for (int k0 = 0; k0 < K_per_split; k0 += BKg) {
        const int kg = k_begin + k0;
        if constexpr (DMA) {
            __syncthreads();   // protect LDS while prior iter still reading
#pragma unroll
            for (int j = 0; j < 4; j++) {
                const int r = srow + j * 8;
                gload_lds16(A + (size_t)(m0 + r) * lda + kg + scol, &As[r * LDW + scol]);
            }
#pragma unroll
            for (int j = 0; j < 4; j++) {
                const int r = srow + j * 8;
                if (n0 + r < N)
                    gload_lds16(B + (size_t)(n0 + r) * ldb + kg + scol, &Bs[r * LDW + scol]);
            }
            __syncthreads();   // drains vmcnt (lds-dma complete)
        } else {
            const u16* ag = A + (size_t)(m0 + vrow) * lda + kg + vcol;
            uint4 a0 = ((const uint4*)ag)[0];
            uint4 a1 = ((const uint4*)ag)[1];
            uint4 a2 = ((const uint4*)ag)[2];
            uint4 a3 = ((const uint4*)ag)[3];
            uint4 b0 = make_uint4(0,0,0,0), b1 = make_uint4(0,0,0,0);
            uint4 b2 = make_uint4(0,0,0,0), b3 = make_uint4(0,0,0,0);
            if (n0 + vrow < N) {
                const u16* bg = B + (size_t)(n0 + vrow) * ldb + kg + vcol;
                b0 = ((const uint4*)bg)[0];
                b1 = ((const uint4*)bg)[1];
                b2 = ((const uint4*)bg)[2];
                b3 = ((const uint4*)bg)[3];
            }
            __syncthreads();
            *(uint4*)&As[vrow * LDW + vcol]      = a0;
            *(uint4*)&As[vrow * LDW + vcol + 8]  = a1;
            *(uint4*)&As[vrow * LDW + vcol + 16] = a2;
            *(uint4*)&As[vrow * LDW + vcol + 24] = a3;
            *(uint4*)&Bs[vrow * LDW + vcol]      = b0;
            *(uint4*)&Bs[vrow * LDW + vcol + 8]  = b1;
            *(uint4*)&Bs[vrow * LDW + vcol + 16] = b2;
            *(uint4*)&Bs[vrow * LDW + vcol + 24] = b3;
            __syncthreads();
        }
#pragma unroll
        for (int kk = 0; kk < 2; kk++) {
            const int ko = kk * 32 + (lane >> 4) * 8;
            short8 af[4], bfr[4];
#pragma unroll
            for (int i = 0; i < 4; i++)
                af[i] = *(const short8*)&As[(wm + i * 16 + (lane & 15)) * LDW + ko];
#pragma unroll
            for (int j = 0; j < 4; j++)
                bfr[j] = *(const short8*)&Bs[(wn + j * 16 + (lane & 15)) * LDW + ko];
#pragma unroll
            for (int i = 0; i < 4; i++)
#pragma unroll
                for (int j = 0; j < 4; j++)
                    acc[i][j] = __builtin_amdgcn_mfma_f32_16x16x32_bf16(
                        af[i], bfr[j], acc[i][j], 0, 0, 0);
        }
    }

    // Epilogue. C/D layout: col(n)=lane&15, row(m)=(lane>>4)*4+reg  [m89-verified]
    const int cn0 = n0 + wn + (lane & 15);
    const int cm0 = m0 + wm + ((lane >> 4) << 2);
    const size_t zoff = (size_t)blockIdx.z * M * ldc;
#pragma unroll
    for (int i = 0; i < 4; i++) {
#pragma unroll
        for (int j = 0; j < 4; j++) {
            const int n = cn0 + j * 16;
            if (n < N) {
#pragma unroll
                for (int r = 0; r < 4; r++) {
                    const int m = cm0 + i * 16 + r;
                    float v = acc[i][j][r];
                    const size_t off = (size_t)m * ldc + n;
                    if constexpr (EPI == 1) {
                        ((u16*)Cout)[off] = f2b(v);
                    } else if constexpr (EPI == 6) { // bias + softplus -> bf16
                        v += bias[n];
                        float sp = (v > 15.f) ? v : log1pf(__expf(v));
                        ((u16*)Cout)[off] = f2b(sp);
                    } else { // 5: f32 partial store (split-K)
                        ((float*)Cout)[zoff + off] = v;
                    }
                }
            }
        }
    }
}

// reduce 16 split-K partials of x_dbl -> xdblf (f32) + xdblb (bf16)
__global__ void reduce_xdbl(const float* __restrict__ part, float* __restrict__ of,
                            u16* __restrict__ ob)
{
    const int i = blockIdx.x * 256 + threadIdx.x;   // float4 index, [0, 49152)
    if (i >= 49152) return;
    const size_t MN4 = 49152;
    float4 s = ((const float4*)part)[i];
#pragma unroll
    for (int z = 1; z < 16; z++) {
        const float4 p = ((const float4*)part)[z * MN4 + i];
        s.x += p.x; s.y += p.y; s.z += p.z; s.w += p.w;
    }
    ((float4*)of)[i] = s;
    ushort4 o;
    o.x = f2b(s.x); o.y = f2b(s.y); o.z = f2b(s.z); o.w = f2b(s.w);
    ((ushort4*)ob)[i] = o;
}

// reduce 4 split-K partials of out -> f32 out
__global__ void reduce_out(const float* __restrict__ part, float* __restrict__ out)
{
    const int i = blockIdx.x * 256 + threadIdx.x;   // float4 index, [0, 524288)
    const size_t MN4 = 524288;
    float4 s = ((const float4*)part)[i];
#pragma unroll
    for (int z = 1; z < 4; z++) {
        const float4 p = ((const float4*)part)[z * MN4 + i];
        s.x += p.x; s.y += p.y; s.z += p.z; s.w += p.w;
    }
    ((float4*)out)[i] = s;
}

// causal depthwise conv (width 4) + SiLU
__global__ void conv_silu_kernel(const u16* __restrict__ xz, const float* __restrict__ cw,
                                 const float* __restrict__ cb, u16* __restrict__ u)
{
    const int idx = blockIdx.x * 256 + threadIdx.x;   // [0, 2*1024*2048)
    const int d = idx & 2047;
    const int row = idx >> 11;
    const int l = row & 1023;
    float acc = cb[d];
#pragma unroll
    for (int j = 0; j < 4; j++) {
        const int lj = l - 3 + j;
        if (lj >= 0)
            acc += cw[d * 4 + j] * b2f(xz[(size_t)(row - 3 + j) * 4096 + d]);
    }
    const float s = acc / (1.f + __expf(-acc));
    u[(size_t)row * 2048 + d] = f2b(s);
}

// ---- chunked selective scan, 8 states per thread, LDS-staged inputs ----
// delta is bf16.
__global__ __launch_bounds__(256)
void scan_pass1(const u16* __restrict__ delta, const u16* __restrict__ u,
                const float* __restrict__ xdbl, const float* __restrict__ A_log,
                float* __restrict__ aP, float* __restrict__ hpart)
{
    __shared__ u16   dS[CT * 128];   // 16 KB
    __shared__ u16   uS[CT * 128];   // 16 KB
    __shared__ float BS[CT * 16];    //  4 KB

    const int tid  = threadIdx.x;
    const int half = tid & 1;
    const int dloc = tid >> 1;
    const int d0 = blockIdx.x * 128;
    const int d = d0 + dloc;
    const int b = blockIdx.y >> 4;
    const int chunk = blockIdx.y & 15;
    const int bd = b * 2048 + d;
    const size_t row0 = (size_t)b * 1024 + chunk * CT;

    for (int i = tid; i < CT * 128 / 8; i += 256) {
        const int e = i * 8;
        const int t = e >> 7, c = e & 127;
        *(uint4*)&dS[e] = *(const uint4*)&delta[(row0 + t) * 2048 + d0 + c];
        *(uint4*)&uS[e] = *(const uint4*)&u[(row0 + t) * 2048 + d0 + c];
    }
    for (int i = tid; i < CT * 16; i += 256) {
        const int t = i >> 4, n = i & 15;
        BS[i] = xdbl[(row0 + t) * 96 + 64 + n];
    }

    float A_dn[8], h[8], ap[8];
#pragma unroll
    for (int j = 0; j < 8; j++) {
        A_dn[j] = -__expf(A_log[d * 16 + half * 8 + j]);
        h[j] = 0.f; ap[j] = 1.f;
    }
    __syncthreads();

#pragma unroll 4
    for (int t = 0; t < CT; t++) {
        const float dl = b2f(dS[t * 128 + dloc]);
        const float uu = b2f(uS[t * 128 + dloc]);
        const float dlu = dl * uu;
        const float4 B0 = *(const float4*)&BS[t * 16 + half * 8];
        const float4 B1 = *(const float4*)&BS[t * 16 + half * 8 + 4];
        const float Bv[8] = {B0.x, B0.y, B0.z, B0.w, B1.x, B1.y, B1.z, B1.w};
#pragma unroll
        for (int j = 0; j < 8; j++) {
            const float dA = __expf(dl * A_dn[j]);
            h[j] = dA * h[j] + dlu * Bv[j];
            ap[j] *= dA;
        }
    }

    const size_t o = ((size_t)(bd * 16 + chunk) * 16) + half * 8;
    *(float4*)&aP[o]     = make_float4(ap[0], ap[1], ap[2], ap[3]);
    *(float4*)&aP[o + 4] = make_float4(ap[4], ap[5], ap[6], ap[7]);
    *(float4*)&hpart[o]     = make_float4(h[0], h[1], h[2], h[3]);
    *(float4*)&hpart[o + 4] = make_float4(h[4], h[5], h[6], h[7]);
}

__global__ void scan_combine(const float* __restrict__ aP, float* __restrict__ hp)
{
    const int idx = blockIdx.x * 256 + threadIdx.x;  // [0, 65536) = bd*16 + n
    const int n = idx & 15;
    const int bd = idx >> 4;
    float h = 0.f;
    for (int c = 0; c < NCHUNK; c++) {
        const size_t o = ((size_t)(bd * 16 + c) * 16) + n;
        const float a = aP[o];
        const float p = hp[o];
        hp[o] = h;          // exclusive prefix = h_init for chunk c
        h = a * h + p;
    }
}

__global__ __launch_bounds__(256)
void scan_pass2(const u16* __restrict__ delta, const u16* __restrict__ u,
                const float* __restrict__ xdbl, const u16* __restrict__ xz,
                const float* __restrict__ A_log, const float* __restrict__ Dv,
                const float* __restrict__ hinit, u16* __restrict__ ybuf)
{
    __shared__ u16   dS[CT * 128];   // 16 KB
    __shared__ u16   uS[CT * 128];   // 16 KB
    __shared__ u16   zS[CT * 128];   // 16 KB
    __shared__ float BS[CT * 16];    //  4 KB
    __shared__ float CS[CT * 16];    //  4 KB

    const int tid  = threadIdx.x;
    const int half = tid & 1;
    const int dloc = tid >> 1;
    const int d0 = blockIdx.x * 128;
    const int d = d0 + dloc;
    const int b = blockIdx.y >> 4;
    const int chunk = blockIdx.y & 15;
    const int bd = b * 2048 + d;
    const size_t row0 = (size_t)b * 1024 + chunk * CT;

    for (int i = tid; i < CT * 128 / 8; i += 256) {
        const int e = i * 8;
        const int t = e >> 7, c = e & 127;
        *(uint4*)&dS[e] = *(const uint4*)&delta[(row0 + t) * 2048 + d0 + c];
        *(uint4*)&uS[e] = *(const uint4*)&u[(row0 + t) * 2048 + d0 + c];
        *(uint4*)&zS[e] = *(const uint4*)&xz[(row0 + t) * 4096 + 2048 + d0 + c];
    }
    for (int i = tid; i < CT * 16; i += 256) {
        const int t = i >> 4, n = i & 15;
        BS[i] = xdbl[(row0 + t) * 96 + 64 + n];
        CS[i] = xdbl[(row0 + t) * 96 + 80 + n];
    }

    const size_t o = ((size_t)(bd * 16 + chunk) * 16) + half * 8;
    const float4 h0 = *(const float4*)&hinit[o];
    const float4 h1 = *(const float4*)&hinit[o + 4];
    float h[8] = {h0.x, h0.y, h0.z, h0.w, h1.x, h1.y, h1.z, h1.w};
    float A_dn[8];
#pragma unroll
    for (int j = 0; j < 8; j++)
        A_dn[j] = -__expf(A_log[d * 16 + half * 8 + j]);
    const float Dd = Dv[d];
    __syncthreads();

#pragma unroll 4
    for (int t = 0; t < CT; t++) {
        const float dl = b2f(dS[t * 128 + dloc]);
        const float uu = b2f(uS[t * 128 + dloc]);
        const float dlu = dl * uu;
        const float4 B0 = *(const float4*)&BS[t * 16 + half * 8];
        const float4 B1 = *(const float4*)&BS[t * 16 + half * 8 + 4];
        const float4 C0 = *(const float4*)&CS[t * 16 + half * 8];
        const float4 C1 = *(const float4*)&CS[t * 16 + half * 8 + 4];
        const float Bv[8] = {B0.x, B0.y, B0.z, B0.w, B1.x, B1.y, B1.z, B1.w};
        const float Cv[8] = {C0.x, C0.y, C0.z, C0.w, C1.x, C1.y, C1.z, C1.w};
        float p = 0.f;
#pragma unroll
        for (int j = 0; j < 8; j++) {
            const float dA = __expf(dl * A_dn[j]);
            h[j] = dA * h[j] + dlu * Bv[j];
            p += h[j] * Cv[j];
        }
        p += __shfl_xor(p, 1);
        if (half == 0) {
            const float z = b2f(zS[t * 128 + dloc]);
            const float gt = z / (1.f + __expf(-z));
            ybuf[(row0 + t) * 2048 + d] = f2b((p + uu * Dd) * gt);
        }
    }
}

extern "C" void kernel_launch(void* const* d_in, const int* in_sizes, int n_in,
                              void* d_out, int out_size, void* d_ws, size_t ws_size,
                              hipStream_t stream)
{
    const float* hid    = (const float*)d_in[0];  // [2,1024,1024]
    const float* w_in   = (const float*)d_in[1];  // [4096,1024]
    const float* conv_w = (const float*)d_in[2];  // [2048,1,4]
    const float* conv_b = (const float*)d_in[3];  // [2048]
    const float* w_x    = (const float*)d_in[4];  // [96,2048]
    const float* w_dt   = (const float*)d_in[5];  // [2048,64]
    const float* b_dt   = (const float*)d_in[6];  // [2048]
    const float* A_log  = (const float*)d_in[7];  // [2048,16]
    const float* Dvec   = (const float*)d_in[8];  // [2048]
    const float* w_out  = (const float*)d_in[9];  // [1024,2048]
    float* out = (float*)d_out;                   // [2,1024,1024] f32

    const size_t MB = 1048576;
    char* ws = (char*)d_ws;
    u16*   xz     = (u16*)(ws + 0);                  // 16 MB  [2048,4096] bf16
    u16*   ubuf   = (u16*)(ws + 16 * MB);            //  8 MB  [2048,2048] bf16
    float* part3  = (float*)(ws + 24 * MB);          // 12.6 MB (16 × 2048×96 f32)
    u16*   delta  = (u16*)(ws + 24 * MB);            //  8 MB [2048,2048] bf16 (after part3 dead)
    float* part6  = (float*)(ws + 0);                // 32 MB (4 × 2048×1024 f32)
    float* xdblf  = (float*)(ws + 40 * MB);          // 768 KB [2048,96] f32
    u16*   xdblb  = (u16*)(ws + 40 * MB + 786432);   // 384 KB [2048,96] bf16
    u16*   w_x_b  = (u16*)(ws + 41 * MB + 131072);   // 384 KB
    u16*   w_dt_b = (u16*)(ws + 41 * MB + 524288);   // 256 KB
    u16*   hid_b  = (u16*)(ws + 42 * MB);            // 4 MB (GEMM1 only)
    float* hpart  = (float*)(ws + 42 * MB);          // 4 MB — after hid_b dead
    u16*   w_in_b = (u16*)(ws + 46 * MB);            // 8 MB (GEMM1 only)
    float* aP     = (float*)(ws + 50 * MB);          // 4 MB — after w_in_b dead
    u16*   ybuf   = (u16*)(ws + 46 * MB);            // 8 MB — pass2 writes after aP dead
    u16*   w_out_b= (u16*)(ws + 54 * MB);            // 4 MB
    // total footprint: 58 MB

    // 0) convert all f32 operands to bf16 (single launch)
    convert_all<<<8512, 256, 0, stream>>>(hid, hid_b, w_in, w_in_b, w_x, w_x_b,
                                          w_dt, w_dt_b, w_out, w_out_b);

    // 1) xz = hidden @ in_proj_w.T   [2048,4096]  (DMA staging: 16 k-iters, 512 blocks)
    gemm_nt<1, true><<<dim3(16, 32, 1), 256, 0, stream>>>(hid_b, w_in_b, xz, nullptr,
                                                          2048, 4096, 1024, 1024, 1024, 4096);
    // 2) u = silu(causal_conv(x))    [2048,2048]
    conv_silu_kernel<<<16384, 256, 0, stream>>>(xz, conv_w, conv_b, ubuf);
    // 3) x_dbl = u @ x_proj_w.T      [2048,96]  (split-K 16; VGPR staging: 2 k-iters)
    gemm_nt<5, false><<<dim3(16, 1, 16), 256, 0, stream>>>(ubuf, w_x_b, part3, nullptr,
                                                           2048, 96, 128, 2048, 2048, 96);
    reduce_xdbl<<<192, 256, 0, stream>>>(part3, xdblf, xdblb);
    // 4) delta = softplus(dt_low @ dt_proj_w.T + dt_proj_b)  (VGPR staging: 1 k-iter)
    gemm_nt<6, false><<<dim3(16, 16, 1), 256, 0, stream>>>(xdblb, w_dt_b, delta, b_dt,
                                                           2048, 2048, 64, 96, 64, 2048);
    // 5) chunked selective scan + skip + gate -> ybuf [2048,2048] bf16
    scan_pass1<<<dim3(16, 32), 256, 0, stream>>>(delta, ubuf, xdblf, A_log, aP, hpart);
    scan_combine<<<256, 256, 0, stream>>>(aP, hpart);
    scan_pass2<<<dim3(16, 32), 256, 0, stream>>>(delta, ubuf, xdblf, xz, A_log, Dvec,
                                                 hpart, ybuf);
    // 6) out = y @ out_proj_w.T      [2048,1024]  (split-K 4; DMA staging: 8 k-iters)
    gemm_nt<5, true><<<dim3(16, 8, 4), 256, 0, stream>>>(ybuf, w_out_b, part6, nullptr,
                                                         2048, 1024, 512, 2048, 2048, 1024);
    reduce_out<<<2048, 256, 0, stream>>>(part6, out);
}